// Round 11
// baseline (125.126 us; speedup 1.0000x reference)
//
#include <hip/hip_runtime.h>

#define BATCH 512
#define NC 3
#define TT 4096
#define HH 17
#define NBLK (TT / 4)     // float4 time-blocks per sequence
#define WU_BLKS 8         // 32 warm-up steps (contraction ~0.58^32 ~ 3e-8)
#define NSEQ (BATCH * 2)

typedef __attribute__((ext_vector_type(8))) short short8;
typedef __attribute__((ext_vector_type(16))) float f32x16;

union B8 { unsigned u[4]; short8 s; };

// tanh(x) = 1 - 2/(2^(2x*log2e)+1); exact saturation, ~1e-7 abs error
__device__ __forceinline__ float fast_tanh(float x) {
    float e = exp2f(x * 2.8853900817779268f);
    float r = __builtin_amdgcn_rcpf(e + 1.0f);
    return fmaf(-2.0f, r, 1.0f);
}

__device__ __forceinline__ unsigned cvt_pk_bf16(float lo, float hi) {
    unsigned r;  // r[15:0]=bf16(lo), r[31:16]=bf16(hi), RNE
    asm("v_cvt_pk_bf16_f32 %0, %1, %2" : "=v"(r) : "v"(lo), "v"(hi));
    return r;
}

__device__ __forceinline__ unsigned short bf16_rne(float f) {
    unsigned u = __float_as_uint(f);
    unsigned r = u + 0x7FFFu + ((u >> 16) & 1u);
    return (unsigned short)(r >> 16);
}

// Recurrence over one chunk. Wave = 32 batches (col n = lane&31), one MFMA
// step per time step:  D = [W_hh | W_hh[:,16], W_ih] x [h ; h16, x_t] + bias.
// Weights carried hi+lo bf16 (systematic bias must be corrected); DATA (h, x)
// carried hi-only bf16 — its rounding error is pseudo-random per step,
// contracts through rho~0.58 and averages out in the 4096-step time-mean.
// 4 MFMAs, single accumulator chain (issue-bound regime: count > depth).
// D regs 0..7 of a lane ARE its next-step B fragment k-slots (no cross-lane).
template <int DIR>
__device__ __forceinline__ void run_loop(
    const float4* __restrict__ xp0, const float4* __restrict__ xp1,
    const float4* __restrict__ xp2,
    short8 Ahi, short8 Alo, short8 A2hi, short8 A2lo,
    f32x16 Cb, int g, int blk0, int blkMain, int blkEnd, float* hs) {

    short8 Bhi = {0,0,0,0,0,0,0,0};
    float h16 = 0.0f;

    int t4 = DIR ? (NBLK - 1 - blk0) : blk0;
    float4 ca = xp0[t4], cb = xp1[t4], cc = xp2[t4];
    const int dstep = DIR ? -1 : 1;

    for (int blk = blk0; blk < blkEnd; ++blk) {
        int nt4 = (blk + 1 < blkEnd) ? t4 + dstep : t4;  // clamped prefetch
        float4 na = xp0[nt4], nb = xp1[nt4], nc = xp2[nt4];

        const float flag = (blk >= blkMain) ? 1.0f : 0.0f;  // warm-up mask
        float fa[4] = {ca.x, ca.y, ca.z, ca.w};
        float fb[4] = {cb.x, cb.y, cb.z, cb.w};
        float fc[4] = {cc.x, cc.y, cc.z, cc.w};

#pragma unroll
        for (int k = 0; k < 4; ++k) {
            const int kk = DIR ? (3 - k) : k;
            float xa = fa[kk], xb = fb[kk], xc = fc[kk];

            // B2 = [h16, x0, x1, x2] hi bf16 only (only g==0 lanes live)
            unsigned p0h = cvt_pk_bf16(h16, xa);
            unsigned p1h = cvt_pk_bf16(xb, xc);
            if (g) { p0h = 0; p1h = 0; }
            B8 th; th.u[0] = p0h; th.u[1] = p1h; th.u[2] = 0; th.u[3] = 0;

            // single 4-deep MFMA chain (weight hi+lo, data hi)
            f32x16 D = __builtin_amdgcn_mfma_f32_32x32x16_bf16(Ahi, Bhi, Cb, 0, 0, 0);
            D = __builtin_amdgcn_mfma_f32_32x32x16_bf16(Alo, Bhi, D, 0, 0, 0);
            D = __builtin_amdgcn_mfma_f32_32x32x16_bf16(A2hi, th.s, D, 0, 0, 0);
            D = __builtin_amdgcn_mfma_f32_32x32x16_bf16(A2lo, th.s, D, 0, 0, 0);

            // tanh on live regs (rows <17 live in regs 0..8), accumulate sums
            float ht[9];
#pragma unroll
            for (int r = 0; r < 9; ++r) {
                ht[r] = fast_tanh(D[r]);
                hs[r] = fmaf(ht[r], flag, hs[r]);
            }
            // next-step B fragment: regs 0..7 are exactly this lane's k-slots
            B8 nh;
            nh.u[0] = cvt_pk_bf16(ht[0], ht[1]);
            nh.u[1] = cvt_pk_bf16(ht[2], ht[3]);
            nh.u[2] = cvt_pk_bf16(ht[4], ht[5]);
            nh.u[3] = cvt_pk_bf16(ht[6], ht[7]);
            Bhi = nh.s;
            h16 = ht[8];
        }
        t4 = nt4;
        ca = na; cb = nb; cc = nc;
    }
}

__global__ __launch_bounds__(64) void rnn_kernel(
    const float* __restrict__ x,
    const float* __restrict__ W_ih_f, const float* __restrict__ W_hh_f,
    const float* __restrict__ b_ih_f, const float* __restrict__ b_hh_f,
    const float* __restrict__ W_ih_b, const float* __restrict__ W_hh_b,
    const float* __restrict__ b_ih_b, const float* __restrict__ b_hh_b,
    float* __restrict__ partial, int nchunk, int bpc) {
    int wid = blockIdx.x;
    int chunk = wid % nchunk;
    int q = wid / nchunk;
    int dir = q & 1;
    int grp = q >> 1;            // 0..15 (batch groups of 32)
    int lane = threadIdx.x;
    int n = lane & 31;           // column = batch within group
    int g = lane >> 5;           // k-block / row-block selector
    int m = n;                   // A-operand row owned by this lane
    int bn = grp * 32 + n;

    const float* W_ih = dir ? W_ih_b : W_ih_f;
    const float* W_hh = dir ? W_hh_b : W_hh_f;
    const float* b_ih = dir ? b_ih_b : b_ih_f;
    const float* b_hh = dir ? b_hh_b : b_hh_f;

    // A fragment: rows m (pad >=17 with 0), k-slots {4g+i, 8+4g+i}
    short8 Ahi, Alo, A2hi, A2lo;
#pragma unroll
    for (int i = 0; i < 8; ++i) {
        int k = (i < 4) ? (4 * g + i) : (8 + 4 * g + (i - 4));
        float wv = (m < HH && k < HH) ? W_hh[m * HH + k] : 0.0f;
        unsigned short hb = bf16_rne(wv);
        float hf = __uint_as_float(((unsigned)hb) << 16);
        Ahi[i] = (short)hb;
        Alo[i] = (short)bf16_rne(wv - hf);
        // A2: k2-slots {16+4g+i, 24+4g+i}: k2==16 -> W_hh[:,16]; 17..19 -> W_ih
        int k2 = (i < 4) ? (16 + 4 * g + i) : (24 + 4 * g + (i - 4));
        float wv2 = 0.0f;
        if (m < HH) {
            if (k2 == 16) wv2 = W_hh[m * HH + 16];
            else if (k2 >= 17 && k2 <= 19) wv2 = W_ih[m * NC + (k2 - 17)];
        }
        unsigned short hb2 = bf16_rne(wv2);
        float hf2 = __uint_as_float(((unsigned)hb2) << 16);
        A2hi[i] = (short)hb2;
        A2lo[i] = (short)bf16_rne(wv2 - hf2);
    }

    // C bias: reg r holds row (r&3)+8*(r>>2)+4g; zero for dead rows
    f32x16 Cb;
#pragma unroll
    for (int r = 0; r < 16; ++r) {
        int row = (r & 3) + 8 * (r >> 2) + 4 * g;
        Cb[r] = (row < HH) ? (b_ih[row] + b_hh[row]) : 0.0f;
    }

    int blkMain = chunk * bpc;
    int blk0 = chunk ? (blkMain - WU_BLKS) : 0;
    int blkEnd = blkMain + bpc;

    const float* xb = x + (size_t)bn * NC * TT;
    const float4* xp0 = reinterpret_cast<const float4*>(xb);
    const float4* xp1 = reinterpret_cast<const float4*>(xb + TT);
    const float4* xp2 = reinterpret_cast<const float4*>(xb + 2 * TT);

    float hs[9];
#pragma unroll
    for (int r = 0; r < 9; ++r) hs[r] = 0.0f;

    if (dir == 0)
        run_loop<0>(xp0, xp1, xp2, Ahi, Alo, A2hi, A2lo, Cb, g, blk0, blkMain, blkEnd, hs);
    else
        run_loop<1>(xp0, xp1, xp2, Ahi, Alo, A2hi, A2lo, Cb, g, blk0, blkMain, blkEnd, hs);

    int seq = bn * 2 + dir;
#pragma unroll
    for (int r = 0; r < 9; ++r) {
        int row = (r & 3) + 8 * (r >> 2) + 4 * g;
        if (row < HH)
            partial[((size_t)seq * nchunk + chunk) * HH + row] = hs[r];
    }
}

// Parallel chunk reduction: one thread per (seq, comp) = 17408 threads, each
// sums nchunk values with 4 independent accumulators (loads pipeline).
__global__ __launch_bounds__(256) void reduce_kernel(
    const float* __restrict__ partial, float* __restrict__ tot, int nchunk) {
    int t = blockIdx.x * blockDim.x + threadIdx.x;
    if (t >= NSEQ * HH) return;
    int seq = t / HH;
    int comp = t - seq * HH;
    const float* p = partial + (size_t)seq * nchunk * HH + comp;
    float s0 = 0.0f, s1 = 0.0f, s2 = 0.0f, s3 = 0.0f;
    int c = 0;
    for (; c + 4 <= nchunk; c += 4) {
        s0 += p[(size_t)(c + 0) * HH];
        s1 += p[(size_t)(c + 1) * HH];
        s2 += p[(size_t)(c + 2) * HH];
        s3 += p[(size_t)(c + 3) * HH];
    }
    for (; c < nchunk; ++c) s0 += p[(size_t)c * HH];
    tot[t] = (s0 + s1) + (s2 + s3);
}

// Tiny conv epilogue: one thread per batch reads its 34 contiguous totals.
__global__ void conv_kernel(const float* __restrict__ tot,
                            const float* __restrict__ conv_w,
                            const float* __restrict__ conv_b,
                            float* __restrict__ out) {
    int b = blockIdx.x * blockDim.x + threadIdx.x;
    if (b >= BATCH) return;
    const float* pf = tot + (size_t)(b * 2 + 0) * HH;  // fwd then bwd: contiguous
    const float inv = 1.0f / (float)TT;
#pragma unroll
    for (int o = 0; o < 2; ++o) {
        float s = 0.0f;
#pragma unroll
        for (int i = 0; i < 2 * HH; ++i) s += conv_w[o * 2 * HH + i] * pf[i];
        out[b * 2 + o] = fmaf(s, inv, conv_b[o]);
    }
}

extern "C" void kernel_launch(void* const* d_in, const int* in_sizes, int n_in,
                              void* d_out, int out_size, void* d_ws, size_t ws_size,
                              hipStream_t stream) {
    const float* x      = (const float*)d_in[0];
    const float* W_ih_f = (const float*)d_in[1];
    const float* W_hh_f = (const float*)d_in[2];
    const float* b_ih_f = (const float*)d_in[3];
    const float* b_hh_f = (const float*)d_in[4];
    const float* W_ih_b = (const float*)d_in[5];
    const float* W_hh_b = (const float*)d_in[6];
    const float* b_ih_b = (const float*)d_in[7];
    const float* b_hh_b = (const float*)d_in[8];
    const float* conv_w = (const float*)d_in[9];
    const float* conv_b = (const float*)d_in[10];

    // ws: partial [NSEQ][nchunk][17] floats, then tot [NSEQ*17] floats
    const size_t tot_bytes = (size_t)NSEQ * HH * 4;
    int nchunk = 128;
    while (nchunk > 8 &&
           ws_size < (size_t)NSEQ * nchunk * HH * 4 + tot_bytes)
        nchunk >>= 1;
    int bpc = NBLK / nchunk;
    float* partial = (float*)d_ws;
    float* tot = partial + (size_t)NSEQ * nchunk * HH;
    float* out = (float*)d_out;

    rnn_kernel<<<dim3(32 * nchunk), dim3(64), 0, stream>>>(
        x, W_ih_f, W_hh_f, b_ih_f, b_hh_f, W_ih_b, W_hh_b, b_ih_b, b_hh_b,
        partial, nchunk, bpc);
    reduce_kernel<<<dim3((NSEQ * HH + 255) / 256), dim3(256), 0, stream>>>(
        partial, tot, nchunk);
    conv_kernel<<<dim3((BATCH + 255) / 256), dim3(256), 0, stream>>>(
        tot, conv_w, conv_b, out);
}

// Round 12
// 98.898 us; speedup vs baseline: 1.2652x; 1.2652x over previous
//
#include <hip/hip_runtime.h>

#define BATCH 512
#define NC 3
#define TT 4096
#define HH 17
#define NBLK (TT / 4)     // float4 time-blocks per sequence
#define WU_BLKS 8         // 32 warm-up steps (contraction ~0.58^32 ~ 3e-8)
#define NSEQ (BATCH * 2)

typedef __attribute__((ext_vector_type(8))) short short8;
typedef __attribute__((ext_vector_type(16))) float f32x16;

union B8 { unsigned u[4]; short8 s; };

// tanh(x) = 1 - 2/(2^(2x*log2e)+1); exact saturation, ~1e-7 abs error
__device__ __forceinline__ float fast_tanh(float x) {
    float e = exp2f(x * 2.8853900817779268f);
    float r = __builtin_amdgcn_rcpf(e + 1.0f);
    return fmaf(-2.0f, r, 1.0f);
}

__device__ __forceinline__ unsigned cvt_pk_bf16(float lo, float hi) {
    unsigned r;  // r[15:0]=bf16(lo), r[31:16]=bf16(hi), RNE
    asm("v_cvt_pk_bf16_f32 %0, %1, %2" : "=v"(r) : "v"(lo), "v"(hi));
    return r;
}

__device__ __forceinline__ unsigned short bf16_rne(float f) {
    unsigned u = __float_as_uint(f);
    unsigned r = u + 0x7FFFu + ((u >> 16) & 1u);
    return (unsigned short)(r >> 16);
}

// x[B][C][T] float4-view -> xT[C][T4][B] float4: lane-contiguous for the RNN.
// LDS-tiled 32x32, coalesced reads AND writes.
__global__ __launch_bounds__(256) void transpose_kernel(
    const float4* __restrict__ x4, float4* __restrict__ xT4) {
    __shared__ float4 tile[32][33];
    int bid = blockIdx.x;
    int tb = bid & 15;          // batch tile
    int tt = (bid >> 4) & 31;   // t4 tile
    int c  = bid >> 9;          // channel
    int b0 = tb * 32, t40 = tt * 32;
    int jr = threadIdx.x & 31, pr = threadIdx.x >> 5;
#pragma unroll
    for (int p = 0; p < 4; ++p) {
        int r = p * 8 + pr;
        tile[r][jr] = x4[(size_t)(b0 + r) * (NC * NBLK) + c * NBLK + t40 + jr];
    }
    __syncthreads();
#pragma unroll
    for (int p = 0; p < 4; ++p) {
        int j = p * 8 + pr;
        xT4[(size_t)(c * NBLK + t40 + j) * BATCH + b0 + jr] = tile[jr][j];
    }
}

// Recurrence over one chunk. Wave = 32 batches (col n = lane&31), one MFMA
// step per time step:  D = [W_hh | W_hh[:,16], W_ih] x [h ; h16, x_t] + bias.
// Weights hi+lo bf16 (systematic); data hi-only (pseudo-random rounding,
// contracts + averages out). 4 MFMAs, single chain (issue-bound regime).
// D regs 0..7 of a lane ARE its next-step B fragment k-slots (no cross-lane).
// tstride: float4 distance between consecutive time-blocks (512 transposed,
// 1 direct fallback). [round-10/11-verified math — only load path changed]
template <int DIR>
__device__ __forceinline__ void run_loop(
    const float4* __restrict__ p0, const float4* __restrict__ p1,
    const float4* __restrict__ p2, int tstride,
    short8 Ahi, short8 Alo, short8 A2hi, short8 A2lo,
    f32x16 Cb, int g, int blk0, int blkMain, int blkEnd, float* hs) {

    short8 Bhi = {0,0,0,0,0,0,0,0};
    float h16 = 0.0f;

    int t4 = DIR ? (NBLK - 1 - blk0) : blk0;
    float4 ca = p0[(size_t)t4 * tstride];
    float4 cb = p1[(size_t)t4 * tstride];
    float4 cc = p2[(size_t)t4 * tstride];
    const int dstep = DIR ? -1 : 1;

    for (int blk = blk0; blk < blkEnd; ++blk) {
        int nt4 = (blk + 1 < blkEnd) ? t4 + dstep : t4;  // clamped prefetch
        float4 na = p0[(size_t)nt4 * tstride];
        float4 nb = p1[(size_t)nt4 * tstride];
        float4 nc = p2[(size_t)nt4 * tstride];

        const float flag = (blk >= blkMain) ? 1.0f : 0.0f;  // warm-up mask
        float fa[4] = {ca.x, ca.y, ca.z, ca.w};
        float fb[4] = {cb.x, cb.y, cb.z, cb.w};
        float fc[4] = {cc.x, cc.y, cc.z, cc.w};

#pragma unroll
        for (int k = 0; k < 4; ++k) {
            const int kk = DIR ? (3 - k) : k;
            float xa = fa[kk], xb = fb[kk], xc = fc[kk];

            // B2 = [h16, x0, x1, x2] hi bf16 only (only g==0 lanes live)
            unsigned p0h = cvt_pk_bf16(h16, xa);
            unsigned p1h = cvt_pk_bf16(xb, xc);
            if (g) { p0h = 0; p1h = 0; }
            B8 th; th.u[0] = p0h; th.u[1] = p1h; th.u[2] = 0; th.u[3] = 0;

            // single 4-deep MFMA chain (weight hi+lo, data hi)
            f32x16 D = __builtin_amdgcn_mfma_f32_32x32x16_bf16(Ahi, Bhi, Cb, 0, 0, 0);
            D = __builtin_amdgcn_mfma_f32_32x32x16_bf16(Alo, Bhi, D, 0, 0, 0);
            D = __builtin_amdgcn_mfma_f32_32x32x16_bf16(A2hi, th.s, D, 0, 0, 0);
            D = __builtin_amdgcn_mfma_f32_32x32x16_bf16(A2lo, th.s, D, 0, 0, 0);

            // tanh on live regs (rows <17 live in regs 0..8), accumulate sums
            float ht[9];
#pragma unroll
            for (int r = 0; r < 9; ++r) {
                ht[r] = fast_tanh(D[r]);
                hs[r] = fmaf(ht[r], flag, hs[r]);
            }
            // next-step B fragment: regs 0..7 are exactly this lane's k-slots
            B8 nh;
            nh.u[0] = cvt_pk_bf16(ht[0], ht[1]);
            nh.u[1] = cvt_pk_bf16(ht[2], ht[3]);
            nh.u[2] = cvt_pk_bf16(ht[4], ht[5]);
            nh.u[3] = cvt_pk_bf16(ht[6], ht[7]);
            Bhi = nh.s;
            h16 = ht[8];
        }
        t4 = nt4;
        ca = na; cb = nb; cc = nc;
    }
}

__global__ __launch_bounds__(64) void rnn_kernel(
    const float4* __restrict__ xb4, int tstride,
    const float* __restrict__ W_ih_f, const float* __restrict__ W_hh_f,
    const float* __restrict__ b_ih_f, const float* __restrict__ b_hh_f,
    const float* __restrict__ W_ih_b, const float* __restrict__ W_hh_b,
    const float* __restrict__ b_ih_b, const float* __restrict__ b_hh_b,
    float* __restrict__ partial, int nchunk, int bpc) {
    int wid = blockIdx.x;
    int chunk = wid % nchunk;
    int q = wid / nchunk;
    int dir = q & 1;
    int grp = q >> 1;            // 0..15 (batch groups of 32)
    int lane = threadIdx.x;
    int n = lane & 31;           // column = batch within group
    int g = lane >> 5;           // k-block / row-block selector
    int m = n;                   // A-operand row owned by this lane
    int bn = grp * 32 + n;

    const float* W_ih = dir ? W_ih_b : W_ih_f;
    const float* W_hh = dir ? W_hh_b : W_hh_f;
    const float* b_ih = dir ? b_ih_b : b_ih_f;
    const float* b_hh = dir ? b_hh_b : b_hh_f;

    // A fragment: rows m (pad >=17 with 0), k-slots {4g+i, 8+4g+i}
    short8 Ahi, Alo, A2hi, A2lo;
#pragma unroll
    for (int i = 0; i < 8; ++i) {
        int k = (i < 4) ? (4 * g + i) : (8 + 4 * g + (i - 4));
        float wv = (m < HH && k < HH) ? W_hh[m * HH + k] : 0.0f;
        unsigned short hb = bf16_rne(wv);
        float hf = __uint_as_float(((unsigned)hb) << 16);
        Ahi[i] = (short)hb;
        Alo[i] = (short)bf16_rne(wv - hf);
        // A2: k2-slots {16+4g+i, 24+4g+i}: k2==16 -> W_hh[:,16]; 17..19 -> W_ih
        int k2 = (i < 4) ? (16 + 4 * g + i) : (24 + 4 * g + (i - 4));
        float wv2 = 0.0f;
        if (m < HH) {
            if (k2 == 16) wv2 = W_hh[m * HH + 16];
            else if (k2 >= 17 && k2 <= 19) wv2 = W_ih[m * NC + (k2 - 17)];
        }
        unsigned short hb2 = bf16_rne(wv2);
        float hf2 = __uint_as_float(((unsigned)hb2) << 16);
        A2hi[i] = (short)hb2;
        A2lo[i] = (short)bf16_rne(wv2 - hf2);
    }

    // C bias: reg r holds row (r&3)+8*(r>>2)+4g; zero for dead rows
    f32x16 Cb;
#pragma unroll
    for (int r = 0; r < 16; ++r) {
        int row = (r & 3) + 8 * (r >> 2) + 4 * g;
        Cb[r] = (row < HH) ? (b_ih[row] + b_hh[row]) : 0.0f;
    }

    int blkMain = chunk * bpc;
    int blk0 = chunk ? (blkMain - WU_BLKS) : 0;
    int blkEnd = blkMain + bpc;

    // channel base pointers (transposed: lane-contiguous; direct: row-major)
    const float4 *p0, *p1, *p2;
    if (tstride == 1) {
        const float4* base = xb4 + (size_t)bn * (NC * NBLK);
        p0 = base; p1 = base + NBLK; p2 = base + 2 * NBLK;
    } else {
        p0 = xb4 + bn;
        p1 = p0 + (size_t)NBLK * BATCH;
        p2 = p0 + (size_t)2 * NBLK * BATCH;
    }

    float hs[9];
#pragma unroll
    for (int r = 0; r < 9; ++r) hs[r] = 0.0f;

    if (dir == 0)
        run_loop<0>(p0, p1, p2, tstride, Ahi, Alo, A2hi, A2lo, Cb, g, blk0, blkMain, blkEnd, hs);
    else
        run_loop<1>(p0, p1, p2, tstride, Ahi, Alo, A2hi, A2lo, Cb, g, blk0, blkMain, blkEnd, hs);

    int seq = bn * 2 + dir;
#pragma unroll
    for (int r = 0; r < 9; ++r) {
        int row = (r & 3) + 8 * (r >> 2) + 4 * g;
        if (row < HH)
            partial[((size_t)seq * nchunk + chunk) * HH + row] = hs[r];
    }
}

// Parallel chunk reduction: one thread per (seq, comp) = 17408 threads, each
// sums nchunk values with 4 independent accumulators (loads pipeline).
__global__ __launch_bounds__(256) void reduce_kernel(
    const float* __restrict__ partial, float* __restrict__ tot, int nchunk) {
    int t = blockIdx.x * blockDim.x + threadIdx.x;
    if (t >= NSEQ * HH) return;
    int seq = t / HH;
    int comp = t - seq * HH;
    const float* p = partial + (size_t)seq * nchunk * HH + comp;
    float s0 = 0.0f, s1 = 0.0f, s2 = 0.0f, s3 = 0.0f;
    int c = 0;
    for (; c + 4 <= nchunk; c += 4) {
        s0 += p[(size_t)(c + 0) * HH];
        s1 += p[(size_t)(c + 1) * HH];
        s2 += p[(size_t)(c + 2) * HH];
        s3 += p[(size_t)(c + 3) * HH];
    }
    for (; c < nchunk; ++c) s0 += p[(size_t)c * HH];
    tot[t] = (s0 + s1) + (s2 + s3);
}

// Tiny conv epilogue: one thread per batch reads its 34 contiguous totals.
__global__ void conv_kernel(const float* __restrict__ tot,
                            const float* __restrict__ conv_w,
                            const float* __restrict__ conv_b,
                            float* __restrict__ out) {
    int b = blockIdx.x * blockDim.x + threadIdx.x;
    if (b >= BATCH) return;
    const float* pf = tot + (size_t)(b * 2 + 0) * HH;  // fwd then bwd: contiguous
    const float inv = 1.0f / (float)TT;
#pragma unroll
    for (int o = 0; o < 2; ++o) {
        float s = 0.0f;
#pragma unroll
        for (int i = 0; i < 2 * HH; ++i) s += conv_w[o * 2 * HH + i] * pf[i];
        out[b * 2 + o] = fmaf(s, inv, conv_b[o]);
    }
}

extern "C" void kernel_launch(void* const* d_in, const int* in_sizes, int n_in,
                              void* d_out, int out_size, void* d_ws, size_t ws_size,
                              hipStream_t stream) {
    const float* x      = (const float*)d_in[0];
    const float* W_ih_f = (const float*)d_in[1];
    const float* W_hh_f = (const float*)d_in[2];
    const float* b_ih_f = (const float*)d_in[3];
    const float* b_hh_f = (const float*)d_in[4];
    const float* W_ih_b = (const float*)d_in[5];
    const float* W_hh_b = (const float*)d_in[6];
    const float* b_ih_b = (const float*)d_in[7];
    const float* b_hh_b = (const float*)d_in[8];
    const float* conv_w = (const float*)d_in[9];
    const float* conv_b = (const float*)d_in[10];

    // ws layout: [xT 25.2 MB if it fits] [partial] [tot]
    const size_t xT_bytes = (size_t)BATCH * NC * TT * 4;
    const size_t tot_bytes = (size_t)NSEQ * HH * 4;
    const size_t pbytes1 = (size_t)NSEQ * HH * 4;  // per chunk
    bool tr = ws_size >= xT_bytes + 8 * pbytes1 + tot_bytes;
    size_t pbase = tr ? xT_bytes : 0;
    int nchunk = 128;
    while (nchunk > 8 && ws_size < pbase + (size_t)nchunk * pbytes1 + tot_bytes)
        nchunk >>= 1;
    int bpc = NBLK / nchunk;

    float* xT = (float*)d_ws;
    float* partial = (float*)((char*)d_ws + pbase);
    float* tot = partial + (size_t)NSEQ * nchunk * HH;
    float* out = (float*)d_out;

    const float4* xb4;
    int tstride;
    if (tr) {
        transpose_kernel<<<dim3(16 * 32 * NC), dim3(256), 0, stream>>>(
            (const float4*)x, (float4*)xT);
        xb4 = (const float4*)xT;
        tstride = BATCH;
    } else {
        xb4 = (const float4*)x;
        tstride = 1;
    }

    rnn_kernel<<<dim3(32 * nchunk), dim3(64), 0, stream>>>(
        xb4, tstride, W_ih_f, W_hh_f, b_ih_f, b_hh_f,
        W_ih_b, W_hh_b, b_ih_b, b_hh_b, partial, nchunk, bpc);
    reduce_kernel<<<dim3((NSEQ * HH + 255) / 256), dim3(256), 0, stream>>>(
        partial, tot, nchunk);
    conv_kernel<<<dim3((BATCH + 255) / 256), dim3(256), 0, stream>>>(
        tot, conv_w, conv_b, out);
}

// Round 13
// 74.479 us; speedup vs baseline: 1.6800x; 1.3279x over previous
//
#include <hip/hip_runtime.h>

#define BATCH 512
#define NC 3
#define TT 4096
#define HH 17
#define NBLK (TT / 4)     // float4 time-blocks per sequence
#define WU_BLKS 5         // 20 warm-up steps (contraction ~0.58^20 ~ 2e-5)
#define NSEQ (BATCH * 2)

typedef __attribute__((ext_vector_type(8))) short short8;
typedef __attribute__((ext_vector_type(16))) float f32x16;

union B8 { unsigned u[4]; short8 s; };

__device__ __forceinline__ float fast_exp2(float y) {
#if __has_builtin(__builtin_amdgcn_exp2f)
    return __builtin_amdgcn_exp2f(y);   // bare v_exp_f32, no denormal fixup code
#else
    return exp2f(y);
#endif
}

// tanh(x) = 1 - 2/(2^(2x*log2e)+1); exact saturation, ~1e-7 abs error.
// Inputs are normal-range (|arg|<=~10) so raw v_exp_f32 == exp2f here.
__device__ __forceinline__ float fast_tanh(float x) {
    float e = fast_exp2(x * 2.8853900817779268f);
    float r = __builtin_amdgcn_rcpf(e + 1.0f);
    return fmaf(-2.0f, r, 1.0f);
}

__device__ __forceinline__ unsigned cvt_pk_bf16(float lo, float hi) {
    unsigned r;  // r[15:0]=bf16(lo), r[31:16]=bf16(hi), RNE
    asm("v_cvt_pk_bf16_f32 %0, %1, %2" : "=v"(r) : "v"(lo), "v"(hi));
    return r;
}

__device__ __forceinline__ unsigned short bf16_rne(float f) {
    unsigned u = __float_as_uint(f);
    unsigned r = u + 0x7FFFu + ((u >> 16) & 1u);
    return (unsigned short)(r >> 16);
}

// x[B][C][T] float4-view -> xT[C][T4][B] float4: lane-contiguous for the RNN.
// LDS-tiled 32x32, coalesced reads AND writes.
__global__ __launch_bounds__(256) void transpose_kernel(
    const float4* __restrict__ x4, float4* __restrict__ xT4) {
    __shared__ float4 tile[32][33];
    int bid = blockIdx.x;
    int tb = bid & 15;          // batch tile
    int tt = (bid >> 4) & 31;   // t4 tile
    int c  = bid >> 9;          // channel
    int b0 = tb * 32, t40 = tt * 32;
    int jr = threadIdx.x & 31, pr = threadIdx.x >> 5;
#pragma unroll
    for (int p = 0; p < 4; ++p) {
        int r = p * 8 + pr;
        tile[r][jr] = x4[(size_t)(b0 + r) * (NC * NBLK) + c * NBLK + t40 + jr];
    }
    __syncthreads();
#pragma unroll
    for (int p = 0; p < 4; ++p) {
        int j = p * 8 + pr;
        xT4[(size_t)(c * NBLK + t40 + j) * BATCH + b0 + jr] = tile[jr][j];
    }
}

// Recurrence over one chunk. Wave = 32 batches (col n = lane&31), one MFMA
// step per time step:  D = [W_hh | W_hh[:,16], W_ih] x [h ; h16, x_t] + bias.
// Weights hi+lo bf16 (systematic); data hi-only (pseudo-random rounding,
// contracts + averages out). 4 MFMAs, single chain (issue-bound regime).
// D regs 0..7 of a lane ARE its next-step B fragment k-slots (no cross-lane).
// tstride: float4 distance between consecutive time-blocks (512 transposed,
// 1 direct fallback). [round-12-verified structure — only tanh/WU changed]
template <int DIR>
__device__ __forceinline__ void run_loop(
    const float4* __restrict__ p0, const float4* __restrict__ p1,
    const float4* __restrict__ p2, int tstride,
    short8 Ahi, short8 Alo, short8 A2hi, short8 A2lo,
    f32x16 Cb, int g, int blk0, int blkMain, int blkEnd, float* hs) {

    short8 Bhi = {0,0,0,0,0,0,0,0};
    float h16 = 0.0f;

    int t4 = DIR ? (NBLK - 1 - blk0) : blk0;
    float4 ca = p0[(size_t)t4 * tstride];
    float4 cb = p1[(size_t)t4 * tstride];
    float4 cc = p2[(size_t)t4 * tstride];
    const int dstep = DIR ? -1 : 1;

    for (int blk = blk0; blk < blkEnd; ++blk) {
        int nt4 = (blk + 1 < blkEnd) ? t4 + dstep : t4;  // clamped prefetch
        float4 na = p0[(size_t)nt4 * tstride];
        float4 nb = p1[(size_t)nt4 * tstride];
        float4 nc = p2[(size_t)nt4 * tstride];

        const float flag = (blk >= blkMain) ? 1.0f : 0.0f;  // warm-up mask
        float fa[4] = {ca.x, ca.y, ca.z, ca.w};
        float fb[4] = {cb.x, cb.y, cb.z, cb.w};
        float fc[4] = {cc.x, cc.y, cc.z, cc.w};

#pragma unroll
        for (int k = 0; k < 4; ++k) {
            const int kk = DIR ? (3 - k) : k;
            float xa = fa[kk], xb = fb[kk], xc = fc[kk];

            // B2 = [h16, x0, x1, x2] hi bf16 only (only g==0 lanes live)
            unsigned p0h = cvt_pk_bf16(h16, xa);
            unsigned p1h = cvt_pk_bf16(xb, xc);
            if (g) { p0h = 0; p1h = 0; }
            B8 th; th.u[0] = p0h; th.u[1] = p1h; th.u[2] = 0; th.u[3] = 0;

            // single 4-deep MFMA chain (weight hi+lo, data hi)
            f32x16 D = __builtin_amdgcn_mfma_f32_32x32x16_bf16(Ahi, Bhi, Cb, 0, 0, 0);
            D = __builtin_amdgcn_mfma_f32_32x32x16_bf16(Alo, Bhi, D, 0, 0, 0);
            D = __builtin_amdgcn_mfma_f32_32x32x16_bf16(A2hi, th.s, D, 0, 0, 0);
            D = __builtin_amdgcn_mfma_f32_32x32x16_bf16(A2lo, th.s, D, 0, 0, 0);

            // tanh on live regs (rows <17 live in regs 0..8), accumulate sums
            float ht[9];
#pragma unroll
            for (int r = 0; r < 9; ++r) {
                ht[r] = fast_tanh(D[r]);
                hs[r] = fmaf(ht[r], flag, hs[r]);
            }
            // next-step B fragment: regs 0..7 are exactly this lane's k-slots
            B8 nh;
            nh.u[0] = cvt_pk_bf16(ht[0], ht[1]);
            nh.u[1] = cvt_pk_bf16(ht[2], ht[3]);
            nh.u[2] = cvt_pk_bf16(ht[4], ht[5]);
            nh.u[3] = cvt_pk_bf16(ht[6], ht[7]);
            Bhi = nh.s;
            h16 = ht[8];
        }
        t4 = nt4;
        ca = na; cb = nb; cc = nc;
    }
}

__global__ __launch_bounds__(64) void rnn_kernel(
    const float4* __restrict__ xb4, int tstride,
    const float* __restrict__ W_ih_f, const float* __restrict__ W_hh_f,
    const float* __restrict__ b_ih_f, const float* __restrict__ b_hh_f,
    const float* __restrict__ W_ih_b, const float* __restrict__ W_hh_b,
    const float* __restrict__ b_ih_b, const float* __restrict__ b_hh_b,
    float* __restrict__ partial, int nchunk, int bpc) {
    int wid = blockIdx.x;
    int chunk = wid % nchunk;
    int q = wid / nchunk;
    int dir = q & 1;
    int grp = q >> 1;            // 0..15 (batch groups of 32)
    int lane = threadIdx.x;
    int n = lane & 31;           // column = batch within group
    int g = lane >> 5;           // k-block / row-block selector
    int m = n;                   // A-operand row owned by this lane
    int bn = grp * 32 + n;

    const float* W_ih = dir ? W_ih_b : W_ih_f;
    const float* W_hh = dir ? W_hh_b : W_hh_f;
    const float* b_ih = dir ? b_ih_b : b_ih_f;
    const float* b_hh = dir ? b_hh_b : b_hh_f;

    // A fragment: rows m (pad >=17 with 0), k-slots {4g+i, 8+4g+i}
    short8 Ahi, Alo, A2hi, A2lo;
#pragma unroll
    for (int i = 0; i < 8; ++i) {
        int k = (i < 4) ? (4 * g + i) : (8 + 4 * g + (i - 4));
        float wv = (m < HH && k < HH) ? W_hh[m * HH + k] : 0.0f;
        unsigned short hb = bf16_rne(wv);
        float hf = __uint_as_float(((unsigned)hb) << 16);
        Ahi[i] = (short)hb;
        Alo[i] = (short)bf16_rne(wv - hf);
        // A2: k2-slots {16+4g+i, 24+4g+i}: k2==16 -> W_hh[:,16]; 17..19 -> W_ih
        int k2 = (i < 4) ? (16 + 4 * g + i) : (24 + 4 * g + (i - 4));
        float wv2 = 0.0f;
        if (m < HH) {
            if (k2 == 16) wv2 = W_hh[m * HH + 16];
            else if (k2 >= 17 && k2 <= 19) wv2 = W_ih[m * NC + (k2 - 17)];
        }
        unsigned short hb2 = bf16_rne(wv2);
        float hf2 = __uint_as_float(((unsigned)hb2) << 16);
        A2hi[i] = (short)hb2;
        A2lo[i] = (short)bf16_rne(wv2 - hf2);
    }

    // C bias: reg r holds row (r&3)+8*(r>>2)+4g; zero for dead rows
    f32x16 Cb;
#pragma unroll
    for (int r = 0; r < 16; ++r) {
        int row = (r & 3) + 8 * (r >> 2) + 4 * g;
        Cb[r] = (row < HH) ? (b_ih[row] + b_hh[row]) : 0.0f;
    }

    int blkMain = chunk * bpc;
    int blk0 = chunk ? (blkMain - WU_BLKS) : 0;
    int blkEnd = blkMain + bpc;

    // channel base pointers (transposed: lane-contiguous; direct: row-major)
    const float4 *p0, *p1, *p2;
    if (tstride == 1) {
        const float4* base = xb4 + (size_t)bn * (NC * NBLK);
        p0 = base; p1 = base + NBLK; p2 = base + 2 * NBLK;
    } else {
        p0 = xb4 + bn;
        p1 = p0 + (size_t)NBLK * BATCH;
        p2 = p0 + (size_t)2 * NBLK * BATCH;
    }

    float hs[9];
#pragma unroll
    for (int r = 0; r < 9; ++r) hs[r] = 0.0f;

    if (dir == 0)
        run_loop<0>(p0, p1, p2, tstride, Ahi, Alo, A2hi, A2lo, Cb, g, blk0, blkMain, blkEnd, hs);
    else
        run_loop<1>(p0, p1, p2, tstride, Ahi, Alo, A2hi, A2lo, Cb, g, blk0, blkMain, blkEnd, hs);

    int seq = bn * 2 + dir;
#pragma unroll
    for (int r = 0; r < 9; ++r) {
        int row = (r & 3) + 8 * (r >> 2) + 4 * g;
        if (row < HH)
            partial[((size_t)seq * nchunk + chunk) * HH + row] = hs[r];
    }
}

// Parallel chunk reduction: one thread per (seq, comp) = 17408 threads, each
// sums nchunk values with 4 independent accumulators (loads pipeline).
__global__ __launch_bounds__(256) void reduce_kernel(
    const float* __restrict__ partial, float* __restrict__ tot, int nchunk) {
    int t = blockIdx.x * blockDim.x + threadIdx.x;
    if (t >= NSEQ * HH) return;
    int seq = t / HH;
    int comp = t - seq * HH;
    const float* p = partial + (size_t)seq * nchunk * HH + comp;
    float s0 = 0.0f, s1 = 0.0f, s2 = 0.0f, s3 = 0.0f;
    int c = 0;
    for (; c + 4 <= nchunk; c += 4) {
        s0 += p[(size_t)(c + 0) * HH];
        s1 += p[(size_t)(c + 1) * HH];
        s2 += p[(size_t)(c + 2) * HH];
        s3 += p[(size_t)(c + 3) * HH];
    }
    for (; c < nchunk; ++c) s0 += p[(size_t)c * HH];
    tot[t] = (s0 + s1) + (s2 + s3);
}

// Tiny conv epilogue: one thread per batch reads its 34 contiguous totals.
__global__ void conv_kernel(const float* __restrict__ tot,
                            const float* __restrict__ conv_w,
                            const float* __restrict__ conv_b,
                            float* __restrict__ out) {
    int b = blockIdx.x * blockDim.x + threadIdx.x;
    if (b >= BATCH) return;
    const float* pf = tot + (size_t)(b * 2 + 0) * HH;  // fwd then bwd: contiguous
    const float inv = 1.0f / (float)TT;
#pragma unroll
    for (int o = 0; o < 2; ++o) {
        float s = 0.0f;
#pragma unroll
        for (int i = 0; i < 2 * HH; ++i) s += conv_w[o * 2 * HH + i] * pf[i];
        out[b * 2 + o] = fmaf(s, inv, conv_b[o]);
    }
}

extern "C" void kernel_launch(void* const* d_in, const int* in_sizes, int n_in,
                              void* d_out, int out_size, void* d_ws, size_t ws_size,
                              hipStream_t stream) {
    const float* x      = (const float*)d_in[0];
    const float* W_ih_f = (const float*)d_in[1];
    const float* W_hh_f = (const float*)d_in[2];
    const float* b_ih_f = (const float*)d_in[3];
    const float* b_hh_f = (const float*)d_in[4];
    const float* W_ih_b = (const float*)d_in[5];
    const float* W_hh_b = (const float*)d_in[6];
    const float* b_ih_b = (const float*)d_in[7];
    const float* b_hh_b = (const float*)d_in[8];
    const float* conv_w = (const float*)d_in[9];
    const float* conv_b = (const float*)d_in[10];

    // ws layout: [xT 25.2 MB if it fits] [partial] [tot]
    const size_t xT_bytes = (size_t)BATCH * NC * TT * 4;
    const size_t tot_bytes = (size_t)NSEQ * HH * 4;
    const size_t pbytes1 = (size_t)NSEQ * HH * 4;  // per chunk
    bool tr = ws_size >= xT_bytes + 8 * pbytes1 + tot_bytes;
    size_t pbase = tr ? xT_bytes : 0;
    int nchunk = 128;
    while (nchunk > 8 && ws_size < pbase + (size_t)nchunk * pbytes1 + tot_bytes)
        nchunk >>= 1;
    int bpc = NBLK / nchunk;

    float* xT = (float*)d_ws;
    float* partial = (float*)((char*)d_ws + pbase);
    float* tot = partial + (size_t)NSEQ * nchunk * HH;
    float* out = (float*)d_out;

    const float4* xb4;
    int tstride;
    if (tr) {
        transpose_kernel<<<dim3(16 * 32 * NC), dim3(256), 0, stream>>>(
            (const float4*)x, (float4*)xT);
        xb4 = (const float4*)xT;
        tstride = BATCH;
    } else {
        xb4 = (const float4*)x;
        tstride = 1;
    }

    rnn_kernel<<<dim3(32 * nchunk), dim3(64), 0, stream>>>(
        xb4, tstride, W_ih_f, W_hh_f, b_ih_f, b_hh_f,
        W_ih_b, W_hh_b, b_ih_b, b_hh_b, partial, nchunk, bpc);
    reduce_kernel<<<dim3((NSEQ * HH + 255) / 256), dim3(256), 0, stream>>>(
        partial, tot, nchunk);
    conv_kernel<<<dim3((BATCH + 255) / 256), dim3(256), 0, stream>>>(
        tot, conv_w, conv_b, out);
}